// Round 1
// baseline (1353.241 us; speedup 1.0000x reference)
//
#include <hip/hip_runtime.h>
#include <math.h>

#define BB 512
#define NN 200
#define DD 128
#define BNROWS (BB*NN)   // 102400

// ---------------- workspace layout (floats) ----------------
// hv     : BNROWS*128
// ho     : BNROWS*128
// in_in  : BNROWS*128
// in_out : BNROWS*128
// wInT   : 128*128   (wInT[k*128+c]  = w_in[c*128+k])
// wOutT  : 128*128
// wIhT   : 256*384   (wIhT[k*384+j]  = w_ih[j*256+k])
// wHhT   : 128*384   (wHhT[k*384+j]  = w_hh[j*128+k])
#define OFF_HV    ((size_t)0)
#define OFF_HO    ((size_t)BNROWS*128)
#define OFF_II    ((size_t)2*BNROWS*128)
#define OFF_IO    ((size_t)3*BNROWS*128)
#define OFF_WINT  ((size_t)4*BNROWS*128)
#define OFF_WOUTT (OFF_WINT + 128*128)
#define OFF_WIHT  (OFF_WOUTT + 128*128)
#define OFF_WHHT  (OFF_WIHT + 256*384)
#define WS_FLOATS (OFF_WHHT + 128*384)

__device__ inline void fma4(float4& a, float s, const float4& w) {
  a.x = fmaf(s, w.x, a.x); a.y = fmaf(s, w.y, a.y);
  a.z = fmaf(s, w.z, a.z); a.w = fmaf(s, w.w, a.w);
}

// ---------------- K0: generic transpose ----------------
// src is J x K row-major; dst is K x J : dst[k*J + j] = src[j*K + k]
__global__ void ktranspose(float* __restrict__ dst, const float* __restrict__ src,
                           int J, int K) {
  int idx = blockIdx.x * 256 + threadIdx.x;
  if (idx < J * K) {
    int j = idx / K, k = idx - j * K;
    dst[(size_t)k * J + j] = src[idx];
  }
}

// ---------------- K1: hv = hidden@w_in.T + b_in ; ho = hidden@w_out.T + b_out ----
// 32 rows per block, 256 threads. hidden gathered from emb[x].
__global__ __launch_bounds__(256) void k1_hvho(
    const int* __restrict__ x, const float* __restrict__ emb,
    const float* __restrict__ wInT, const float* __restrict__ wOutT,
    const float* __restrict__ b_in, const float* __restrict__ b_out,
    float* __restrict__ hv, float* __restrict__ ho) {
  __shared__ float hid[32][132];   // padded
  __shared__ float wv[32][128];
  __shared__ float wo[32][128];
  const int t = threadIdx.x;
  const int rbase = blockIdx.x * 32;
  // stage hidden tile (gather)
  for (int i = t; i < 32 * 128; i += 256) {
    int r = i >> 7, c = i & 127;
    int xv = x[rbase + r];
    hid[r][c] = emb[(size_t)xv * 128 + c];
  }
  const int rg = t >> 5, cg = t & 31;
  float4 accv[4], acco[4];
  #pragma unroll
  for (int i2 = 0; i2 < 4; ++i2) {
    accv[i2] = make_float4(0.f, 0.f, 0.f, 0.f);
    acco[i2] = make_float4(0.f, 0.f, 0.f, 0.f);
  }
  for (int k0 = 0; k0 < 128; k0 += 32) {
    __syncthreads();
    for (int i = t; i < 32 * 128; i += 256) {
      int kk = i >> 7, c = i & 127;
      wv[kk][c] = wInT[(size_t)(k0 + kk) * 128 + c];
      wo[kk][c] = wOutT[(size_t)(k0 + kk) * 128 + c];
    }
    __syncthreads();
    #pragma unroll 8
    for (int kk = 0; kk < 32; ++kk) {
      float4 v = *(const float4*)&wv[kk][cg * 4];
      float4 o = *(const float4*)&wo[kk][cg * 4];
      #pragma unroll
      for (int i2 = 0; i2 < 4; ++i2) {
        float h = hid[rg + 8 * i2][k0 + kk];
        fma4(accv[i2], h, v);
        fma4(acco[i2], h, o);
      }
    }
  }
  float4 bi = *(const float4*)&b_in[cg * 4];
  float4 bo = *(const float4*)&b_out[cg * 4];
  #pragma unroll
  for (int i2 = 0; i2 < 4; ++i2) {
    int row = rbase + rg + 8 * i2;
    float4 rv = accv[i2]; rv.x += bi.x; rv.y += bi.y; rv.z += bi.z; rv.w += bi.w;
    float4 ro = acco[i2]; ro.x += bo.x; ro.y += bo.y; ro.z += bo.z; ro.w += bo.w;
    *(float4*)&hv[(size_t)row * 128 + cg * 4] = rv;
    *(float4*)&ho[(size_t)row * 128 + cg * 4] = ro;
  }
}

// ---------------- K2: in_in = A[:,:, :200]@hv + b_iah ; in_out = A[:,:,200:]@ho + b_oah
// grid (512, 5): one batch x 40-row tile per block.
__global__ __launch_bounds__(256) void k2_amm(
    const float* __restrict__ A, const float* __restrict__ hv,
    const float* __restrict__ ho,
    const float* __restrict__ b_iah, const float* __restrict__ b_oah,
    float* __restrict__ in_in, float* __restrict__ in_out) {
  const int b = blockIdx.x;
  const int rbase = blockIdx.y * 40;
  __shared__ float Ai[40][48];    // A_in transposed chunk: Ai[m][r]
  __shared__ float Ao[40][48];
  __shared__ float hvC[40][128];
  __shared__ float hoC[40][128];
  const int t = threadIdx.x, rg = t >> 5, cg = t & 31;
  float4 aci[5], aco[5];
  #pragma unroll
  for (int i2 = 0; i2 < 5; ++i2) {
    aci[i2] = make_float4(0.f, 0.f, 0.f, 0.f);
    aco[i2] = make_float4(0.f, 0.f, 0.f, 0.f);
  }
  for (int m0 = 0; m0 < 200; m0 += 40) {
    __syncthreads();
    for (int i = t; i < 40 * 40; i += 256) {
      int r = i / 40, m = i - r * 40;
      const float* arow = &A[(size_t)(b * 200 + rbase + r) * 400];
      Ai[m][r] = arow[m0 + m];
      Ao[m][r] = arow[200 + m0 + m];
    }
    for (int i = t; i < 40 * 128; i += 256) {
      int m = i >> 7, c = i & 127;
      hvC[m][c] = hv[(size_t)(b * 200 + m0 + m) * 128 + c];
      hoC[m][c] = ho[(size_t)(b * 200 + m0 + m) * 128 + c];
    }
    __syncthreads();
    #pragma unroll 4
    for (int m = 0; m < 40; ++m) {
      float4 v = *(const float4*)&hvC[m][cg * 4];
      float4 o = *(const float4*)&hoC[m][cg * 4];
      #pragma unroll
      for (int i2 = 0; i2 < 5; ++i2) {
        float a1 = Ai[m][rg + 8 * i2];
        float a2 = Ao[m][rg + 8 * i2];
        fma4(aci[i2], a1, v);
        fma4(aco[i2], a2, o);
      }
    }
  }
  float4 bi = *(const float4*)&b_iah[cg * 4];
  float4 bo = *(const float4*)&b_oah[cg * 4];
  #pragma unroll
  for (int i2 = 0; i2 < 5; ++i2) {
    int row = b * 200 + rbase + rg + 8 * i2;
    float4 rv = aci[i2]; rv.x += bi.x; rv.y += bi.y; rv.z += bi.z; rv.w += bi.w;
    float4 ro = aco[i2]; ro.x += bo.x; ro.y += bo.y; ro.z += bo.z; ro.w += bo.w;
    *(float4*)&in_in[(size_t)row * 128 + cg * 4] = rv;
    *(float4*)&in_out[(size_t)row * 128 + cg * 4] = ro;
  }
}

// ---------------- K3: gi = [in_in|in_out]@w_ih.T + b_ih ; gh = hidden@w_hh.T + b_hh ;
// gates -> out. 16 rows per block. Each thread owns cols {c..c+3} of all three
// 128-blocks (r/i/n), so the gate triplet stays in registers.
__global__ __launch_bounds__(256) void k3_gates(
    const float* __restrict__ in_in, const float* __restrict__ in_out,
    const int* __restrict__ x, const float* __restrict__ emb,
    const float* __restrict__ wIhT, const float* __restrict__ wHhT,
    const float* __restrict__ b_ih, const float* __restrict__ b_hh,
    float* __restrict__ out) {
  __shared__ float z[16][388];    // [0:128) in_in | [128:256) in_out | [256:384) hid
  __shared__ float wT[16][384];
  const int t = threadIdx.x, rg = t >> 5, cg = t & 31;
  const int rbase = blockIdx.x * 16;
  for (int i = t; i < 16 * 128; i += 256) {
    int r = i >> 7, c = i & 127;
    size_t grow = (size_t)(rbase + r) * 128;
    z[r][c] = in_in[grow + c];
    z[r][128 + c] = in_out[grow + c];
    z[r][256 + c] = emb[(size_t)x[rbase + r] * 128 + c];
  }
  float4 gi[2][3], gh[2][3];
  #pragma unroll
  for (int blk = 0; blk < 3; ++blk) {
    float4 bih = *(const float4*)&b_ih[blk * 128 + cg * 4];
    float4 bhh = *(const float4*)&b_hh[blk * 128 + cg * 4];
    gi[0][blk] = bih; gi[1][blk] = bih;
    gh[0][blk] = bhh; gh[1][blk] = bhh;
  }
  // pass A: gi over k in [0,256)
  for (int k0 = 0; k0 < 256; k0 += 16) {
    __syncthreads();
    for (int i = t; i < 16 * 384; i += 256) {
      int kk = i / 384, j = i - kk * 384;
      wT[kk][j] = wIhT[(size_t)(k0 + kk) * 384 + j];
    }
    __syncthreads();
    #pragma unroll 8
    for (int kk = 0; kk < 16; ++kk) {
      float4 w0 = *(const float4*)&wT[kk][cg * 4];
      float4 w1 = *(const float4*)&wT[kk][128 + cg * 4];
      float4 w2 = *(const float4*)&wT[kk][256 + cg * 4];
      #pragma unroll
      for (int i2 = 0; i2 < 2; ++i2) {
        float zz = z[rg + 8 * i2][k0 + kk];
        fma4(gi[i2][0], zz, w0);
        fma4(gi[i2][1], zz, w1);
        fma4(gi[i2][2], zz, w2);
      }
    }
  }
  // pass B: gh over k in [0,128), z cols 256+
  for (int k0 = 0; k0 < 128; k0 += 16) {
    __syncthreads();
    for (int i = t; i < 16 * 384; i += 256) {
      int kk = i / 384, j = i - kk * 384;
      wT[kk][j] = wHhT[(size_t)(k0 + kk) * 384 + j];
    }
    __syncthreads();
    #pragma unroll 8
    for (int kk = 0; kk < 16; ++kk) {
      float4 w0 = *(const float4*)&wT[kk][cg * 4];
      float4 w1 = *(const float4*)&wT[kk][128 + cg * 4];
      float4 w2 = *(const float4*)&wT[kk][256 + cg * 4];
      #pragma unroll
      for (int i2 = 0; i2 < 2; ++i2) {
        float zz = z[rg + 8 * i2][256 + k0 + kk];
        fma4(gh[i2][0], zz, w0);
        fma4(gh[i2][1], zz, w1);
        fma4(gh[i2][2], zz, w2);
      }
    }
  }
  // gates + store
  #pragma unroll
  for (int i2 = 0; i2 < 2; ++i2) {
    int r = rg + 8 * i2;
    float4 hidv = *(const float4*)&z[r][256 + cg * 4];
    float4 res;
    {
      float hvals[4] = {hidv.x, hidv.y, hidv.z, hidv.w};
      float ir[4] = {gi[i2][0].x, gi[i2][0].y, gi[i2][0].z, gi[i2][0].w};
      float ii[4] = {gi[i2][1].x, gi[i2][1].y, gi[i2][1].z, gi[i2][1].w};
      float in_[4] = {gi[i2][2].x, gi[i2][2].y, gi[i2][2].z, gi[i2][2].w};
      float hr[4] = {gh[i2][0].x, gh[i2][0].y, gh[i2][0].z, gh[i2][0].w};
      float hi[4] = {gh[i2][1].x, gh[i2][1].y, gh[i2][1].z, gh[i2][1].w};
      float hn[4] = {gh[i2][2].x, gh[i2][2].y, gh[i2][2].z, gh[i2][2].w};
      float o[4];
      #pragma unroll
      for (int e = 0; e < 4; ++e) {
        float g_in = 1.f / (1.f + expf(-(ii[e] + hi[e])));
        float g_rs = 1.f / (1.f + expf(-(ir[e] + hr[e])));
        float g_ot = tanhf(in_[e] + g_rs * hn[e]);
        o[e] = g_ot + g_in * (hvals[e] - g_ot);
      }
      res = make_float4(o[0], o[1], o[2], o[3]);
    }
    *(float4*)&out[(size_t)(rbase + r) * 128 + cg * 4] = res;
  }
}

extern "C" void kernel_launch(void* const* d_in, const int* in_sizes, int n_in,
                              void* d_out, int out_size, void* d_ws, size_t ws_size,
                              hipStream_t stream) {
  const int*   x     = (const int*)d_in[0];
  const float* A     = (const float*)d_in[1];
  const float* emb   = (const float*)d_in[2];
  const float* w_in  = (const float*)d_in[3];
  const float* b_in  = (const float*)d_in[4];
  const float* w_out = (const float*)d_in[5];
  const float* b_out = (const float*)d_in[6];
  const float* w_ih  = (const float*)d_in[7];
  const float* b_ih  = (const float*)d_in[8];
  const float* w_hh  = (const float*)d_in[9];
  const float* b_hh  = (const float*)d_in[10];
  const float* b_iah = (const float*)d_in[11];
  const float* b_oah = (const float*)d_in[12];
  float* out = (float*)d_out;
  float* ws = (float*)d_ws;

  if (ws_size < WS_FLOATS * sizeof(float)) return;  // ws too small -> visible failure

  float* hv    = ws + OFF_HV;
  float* ho    = ws + OFF_HO;
  float* in_in = ws + OFF_II;
  float* in_ot = ws + OFF_IO;
  float* wInT  = ws + OFF_WINT;
  float* wOutT = ws + OFF_WOUTT;
  float* wIhT  = ws + OFF_WIHT;
  float* wHhT  = ws + OFF_WHHT;

  ktranspose<<<(128 * 128 + 255) / 256, 256, 0, stream>>>(wInT, w_in, 128, 128);
  ktranspose<<<(128 * 128 + 255) / 256, 256, 0, stream>>>(wOutT, w_out, 128, 128);
  ktranspose<<<(384 * 256 + 255) / 256, 256, 0, stream>>>(wIhT, w_ih, 384, 256);
  ktranspose<<<(384 * 128 + 255) / 256, 256, 0, stream>>>(wHhT, w_hh, 384, 128);

  k1_hvho<<<BNROWS / 32, 256, 0, stream>>>(x, emb, wInT, wOutT, b_in, b_out, hv, ho);

  dim3 g2(BB, 5);
  k2_amm<<<g2, 256, 0, stream>>>(A, hv, ho, b_iah, b_oah, in_in, in_ot);

  k3_gates<<<BNROWS / 16, 256, 0, stream>>>(in_in, in_ot, x, emb, wIhT, wHhT,
                                            b_ih, b_hh, out);
}

// Round 3
// 759.999 us; speedup vs baseline: 1.7806x; 1.7806x over previous
//
#include <hip/hip_runtime.h>
#include <math.h>

#define BB 512
#define NN 200
#define DD 128
#define BNROWS (BB*NN)   // 102400

typedef float f32x4 __attribute__((ext_vector_type(4)));
typedef short bf16x8 __attribute__((ext_vector_type(8)));

#define MFMA16(a,b,c) __builtin_amdgcn_mfma_f32_16x16x32_bf16(a,b,c,0,0,0)

// ---------------- workspace layout (bytes) ----------------
#define OFF_ZHI   ((size_t)0)
#define OFF_ZLO   (OFF_ZHI + (size_t)BNROWS*384*2)
#define OFF_HVT   (OFF_ZLO + (size_t)BNROWS*256*2)
#define OFF_HOT   (OFF_HVT + (size_t)BB*128*224*2)
#define OFF_WINT  (OFF_HOT + (size_t)BB*128*224*2)
#define OFF_WOUTT (OFF_WINT + 128*128*4)
#define OFF_WH    (OFF_WOUTT + 128*128*4)
#define OFF_WL    (OFF_WH + (size_t)512*384*2)
#define OFF_BSUM  (OFF_WL + (size_t)512*384*2)
#define WS_BYTES  (OFF_BSUM + 512*4)

__device__ inline unsigned short f2bf(float x) {
  unsigned int u = __float_as_uint(x);
  unsigned int r = u + 0x7FFFu + ((u >> 16) & 1u);   // RNE
  return (unsigned short)(r >> 16);
}
__device__ inline float bf2f(unsigned short h) {
  return __uint_as_float(((unsigned int)h) << 16);
}
__device__ inline void fma4(f32x4& a, float s, const f32x4& w) {
  a.x = fmaf(s, w.x, a.x); a.y = fmaf(s, w.y, a.y);
  a.z = fmaf(s, w.z, a.z); a.w = fmaf(s, w.w, a.w);
}

// ---------------- K0: generic f32 transpose ----------------
__global__ void ktranspose(float* __restrict__ dst, const float* __restrict__ src,
                           int J, int K) {
  int idx = blockIdx.x * 256 + threadIdx.x;
  if (idx < J * K) {
    int j = idx / K, k = idx - j * K;
    dst[(size_t)k * J + j] = src[idx];
  }
}

// ---------------- Wcat build: permuted 512-col [r | i | n_i | n_h], K=384 ------
__global__ void wcat_build(const float* __restrict__ w_ih, const float* __restrict__ w_hh,
                           const float* __restrict__ b_ih, const float* __restrict__ b_hh,
                           unsigned short* __restrict__ Wh, unsigned short* __restrict__ Wl,
                           float* __restrict__ bsum) {
  int idx = blockIdx.x * 256 + threadIdx.x;   // 512*384
  if (idx >= 512 * 384) return;
  int jp = idx / 384, k = idx - jp * 384;
  int nh = jp >> 8, ng = (jp >> 7) & 1, t = (jp >> 4) & 7, q = jp & 15;
  int blk = t >> 1, s = t & 1;
  int c = nh * 64 + ng * 32 + s * 16 + q;
  int g = (blk <= 1) ? blk : 2;
  float val;
  if (k < 256) val = (blk == 3) ? 0.f : w_ih[(size_t)(g * 128 + c) * 256 + k];
  else         val = (blk == 2) ? 0.f : w_hh[(size_t)(g * 128 + c) * 128 + (k - 256)];
  unsigned short h = f2bf(val);
  Wh[idx] = h;
  Wl[idx] = f2bf(val - bf2f(h));
  if (k == 0) {
    float bv;
    if (blk == 0)      bv = b_ih[c] + b_hh[c];
    else if (blk == 1) bv = b_ih[128 + c] + b_hh[128 + c];
    else if (blk == 2) bv = b_ih[256 + c];
    else               bv = b_hh[256 + c];
    bsum[jp] = bv;
  }
}

// ---------------- K1: hv/ho fp32 GEMM -> transposed bf16 hvT/hoT; hidden -> Z_hi
__global__ __launch_bounds__(256) void k1_hvho(
    const int* __restrict__ x, const float* __restrict__ emb,
    const float* __restrict__ wInT, const float* __restrict__ wOutT,
    const float* __restrict__ b_in, const float* __restrict__ b_out,
    unsigned short* __restrict__ hvT, unsigned short* __restrict__ hoT,
    unsigned short* __restrict__ Z_hi) {
  __shared__ float hid[32][132];
  __shared__ float wv[32][132];
  __shared__ float wo[32][132];
  const int t = threadIdx.x;
  const int b = blockIdx.x;
  const int m0 = blockIdx.y * 32;
  for (int i = t; i < 32 * 128; i += 256) {
    int r = i >> 7, c = i & 127;
    int m = m0 + r;
    int rowc = b * 200 + (m < 200 ? m : 199);
    float h = emb[(size_t)x[rowc] * 128 + c];
    hid[r][c] = h;
    if (m < 200) Z_hi[(size_t)(b * 200 + m) * 384 + 256 + c] = f2bf(h);
  }
  const int rg = t >> 5, cg = t & 31;
  f32x4 accv[4], acco[4];
  #pragma unroll
  for (int i2 = 0; i2 < 4; ++i2) { accv[i2] = 0.f; acco[i2] = 0.f; }
  for (int k0 = 0; k0 < 128; k0 += 32) {
    __syncthreads();
    for (int i = t; i < 32 * 128; i += 256) {
      int kk = i >> 7, c = i & 127;
      wv[kk][c] = wInT[(size_t)(k0 + kk) * 128 + c];
      wo[kk][c] = wOutT[(size_t)(k0 + kk) * 128 + c];
    }
    __syncthreads();
    #pragma unroll 8
    for (int kk = 0; kk < 32; ++kk) {
      f32x4 v = *(const f32x4*)&wv[kk][cg * 4];
      f32x4 o = *(const f32x4*)&wo[kk][cg * 4];
      #pragma unroll
      for (int i2 = 0; i2 < 4; ++i2) {
        float h = hid[rg + 8 * i2][k0 + kk];
        fma4(accv[i2], h, v);
        fma4(acco[i2], h, o);
      }
    }
  }
  f32x4 bi = *(const f32x4*)&b_in[cg * 4];
  f32x4 bo = *(const f32x4*)&b_out[cg * 4];
  __syncthreads();
  #pragma unroll
  for (int i2 = 0; i2 < 4; ++i2) {
    f32x4 rv = accv[i2] + bi;
    f32x4 ro = acco[i2] + bo;
    *(f32x4*)&wv[rg + 8 * i2][cg * 4] = rv;
    *(f32x4*)&wo[rg + 8 * i2][cg * 4] = ro;
  }
  __syncthreads();
  {
    int c = t >> 1, half = t & 1;
    bf16x8 pv0, pv1, po0, po1;
    #pragma unroll
    for (int j = 0; j < 16; ++j) {
      int ml = half * 16 + j;
      bool valid = (m0 + ml) < 200;
      float fv = valid ? wv[ml][c] : 0.f;
      float fo = valid ? wo[ml][c] : 0.f;
      if (j < 8) { pv0[j] = (short)f2bf(fv); po0[j] = (short)f2bf(fo); }
      else       { pv1[j - 8] = (short)f2bf(fv); po1[j - 8] = (short)f2bf(fo); }
    }
    size_t base = ((size_t)(b * 128 + c)) * 224 + m0 + half * 16;
    *(bf16x8*)&hvT[base]     = pv0;
    *(bf16x8*)&hvT[base + 8] = pv1;
    *(bf16x8*)&hoT[base]     = po0;
    *(bf16x8*)&hoT[base + 8] = po1;
  }
}

// ---------------- K2: batched A-matmul via MFMA, A split hi/lo ------
__global__ __launch_bounds__(256) void k2_amm(
    const float* __restrict__ A,
    const unsigned short* __restrict__ hvT, const unsigned short* __restrict__ hoT,
    const float* __restrict__ b_iah, const float* __restrict__ b_oah,
    unsigned short* __restrict__ Z_hi, unsigned short* __restrict__ Z_lo) {
  __shared__ alignas(16) unsigned short Ainh[64][32];
  __shared__ alignas(16) unsigned short Ainl[64][32];
  __shared__ alignas(16) unsigned short Aouth[64][32];
  __shared__ alignas(16) unsigned short Aoutl[64][32];
  __shared__ alignas(16) unsigned short Bv[128][32];
  __shared__ alignas(16) unsigned short Bo[128][32];
  const int t = threadIdx.x;
  const int b = blockIdx.x;
  const int m0 = blockIdx.y * 64;
  const int wv_id = t >> 6, lane = t & 63;
  const int q = lane & 15, quad = lane >> 4;
  const int sel = wv_id >> 1, nh2 = wv_id & 1;
  f32x4 acc[4][4];
  #pragma unroll
  for (int i = 0; i < 4; ++i)
    #pragma unroll
    for (int j = 0; j < 4; ++j) acc[i][j] = 0.f;

  for (int k0 = 0; k0 < 224; k0 += 32) {
    __syncthreads();
    {  // stage A (fp32 -> bf16 hi+lo)
      int m = t >> 2, seg = t & 3;
      int gm = m0 + m, kb = k0 + seg * 8;
      float fin[8], fot[8];
      bool v = (gm < 200) && (kb < 200);
      if (v) {
        const float* arow = A + (size_t)(b * 200 + gm) * 400;
        f32x4 p0 = *(const f32x4*)(arow + kb);
        f32x4 p1 = *(const f32x4*)(arow + kb + 4);
        f32x4 q0 = *(const f32x4*)(arow + 200 + kb);
        f32x4 q1 = *(const f32x4*)(arow + 200 + kb + 4);
        fin[0]=p0.x; fin[1]=p0.y; fin[2]=p0.z; fin[3]=p0.w;
        fin[4]=p1.x; fin[5]=p1.y; fin[6]=p1.z; fin[7]=p1.w;
        fot[0]=q0.x; fot[1]=q0.y; fot[2]=q0.z; fot[3]=q0.w;
        fot[4]=q1.x; fot[5]=q1.y; fot[6]=q1.z; fot[7]=q1.w;
      } else {
        #pragma unroll
        for (int e = 0; e < 8; ++e) { fin[e] = 0.f; fot[e] = 0.f; }
      }
      bf16x8 ih, il, oh, ol;
      #pragma unroll
      for (int e = 0; e < 8; ++e) {
        unsigned short h1 = f2bf(fin[e]);
        ih[e] = (short)h1; il[e] = (short)f2bf(fin[e] - bf2f(h1));
        unsigned short h2 = f2bf(fot[e]);
        oh[e] = (short)h2; ol[e] = (short)f2bf(fot[e] - bf2f(h2));
      }
      *(bf16x8*)&Ainh[m][seg * 8]  = ih;
      *(bf16x8*)&Ainl[m][seg * 8]  = il;
      *(bf16x8*)&Aouth[m][seg * 8] = oh;
      *(bf16x8*)&Aoutl[m][seg * 8] = ol;
    }
    #pragma unroll
    for (int p = 0; p < 2; ++p) {  // stage B (bf16, zero-padded to 224)
      int i = p * 256 + t;
      int c = i >> 2, seg = i & 3;
      size_t off = ((size_t)(b * 128 + c)) * 224 + k0 + seg * 8;
      *(bf16x8*)&Bv[c][seg * 8] = *(const bf16x8*)(hvT + off);
      *(bf16x8*)&Bo[c][seg * 8] = *(const bf16x8*)(hoT + off);
    }
    __syncthreads();
    const unsigned short (*Ath)[32] = sel ? Aouth : Ainh;
    const unsigned short (*Atl)[32] = sel ? Aoutl : Ainl;
    const unsigned short (*Bt)[32]  = sel ? Bo : Bv;
    bf16x8 ah[4], al[4];
    #pragma unroll
    for (int mt = 0; mt < 4; ++mt) {
      ah[mt] = *(const bf16x8*)&Ath[mt * 16 + q][quad * 8];
      al[mt] = *(const bf16x8*)&Atl[mt * 16 + q][quad * 8];
    }
    #pragma unroll
    for (int nt = 0; nt < 4; ++nt) {
      bf16x8 bb = *(const bf16x8*)&Bt[nh2 * 64 + nt * 16 + q][quad * 8];
      #pragma unroll
      for (int mt = 0; mt < 4; ++mt) {
        acc[mt][nt] = MFMA16(ah[mt], bb, acc[mt][nt]);
        acc[mt][nt] = MFMA16(al[mt], bb, acc[mt][nt]);
      }
    }
  }
  const float* bias = sel ? b_oah : b_iah;
  const int colbase = sel * 128;
  #pragma unroll
  for (int nt = 0; nt < 4; ++nt) {
    int c = nh2 * 64 + nt * 16 + q;
    float bi = bias[c];
    #pragma unroll
    for (int mt = 0; mt < 4; ++mt) {
      #pragma unroll
      for (int r = 0; r < 4; ++r) {
        int m = m0 + mt * 16 + quad * 4 + r;
        if (m < 200) {
          float v = acc[mt][nt][r] + bi;
          unsigned short hs = f2bf(v);
          size_t row = (size_t)(b * 200 + m);
          Z_hi[row * 384 + colbase + c] = hs;
          Z_lo[row * 256 + colbase + c] = f2bf(v - bf2f(hs));
        }
      }
    }
  }
}

// ---------------- K3: fused gi/gh GEMM (split-bf16 MFMA) + gates ----------------
// Two compile-time phases; every MFMA and fragment load unconditional.
__global__ __launch_bounds__(256) void k3_gates(
    const unsigned short* __restrict__ Z_hi, const unsigned short* __restrict__ Z_lo,
    const unsigned short* __restrict__ Wh, const unsigned short* __restrict__ Wl,
    const float* __restrict__ bsum, float* __restrict__ out) {
  __shared__ alignas(16) unsigned short Ah[128][32];
  __shared__ alignas(16) unsigned short Al[128][32];
  __shared__ alignas(16) unsigned short WhS[256][32];
  __shared__ alignas(16) unsigned short WlS[256][32];
  const int t = threadIdx.x;
  const int w = t >> 6, lane = t & 63;
  const int q = lane & 15, quad = lane >> 4;
  const int mh = w >> 1, ng = w & 1;
  const size_t rbase = (size_t)blockIdx.x * 128;
  const int nh = blockIdx.y;

  f32x4 acc[4][8];
  #pragma unroll
  for (int i = 0; i < 4; ++i)
    #pragma unroll
    for (int j = 0; j < 8; ++j) acc[i][j] = 0.f;

  // ---- phase 1: k in [0,256) — inputs part; tiles 0..5 (r,i,n_i); 3-term ----
  for (int kc = 0; kc < 8; ++kc) {
    const int k0 = kc * 32;
    __syncthreads();
    #pragma unroll
    for (int p = 0; p < 2; ++p) {
      int i = p * 256 + t;
      int m = i >> 2, seg = i & 3;
      *(bf16x8*)&Ah[m][seg * 8] =
          *(const bf16x8*)(Z_hi + (rbase + m) * 384 + k0 + seg * 8);
      *(bf16x8*)&Al[m][seg * 8] =
          *(const bf16x8*)(Z_lo + (rbase + m) * 256 + k0 + seg * 8);
    }
    #pragma unroll
    for (int p = 0; p < 4; ++p) {
      int i = p * 256 + t;
      int j = i >> 2, seg = i & 3;
      size_t off = (size_t)(nh * 256 + j) * 384 + k0 + seg * 8;
      *(bf16x8*)&WhS[j][seg * 8] = *(const bf16x8*)(Wh + off);
      *(bf16x8*)&WlS[j][seg * 8] = *(const bf16x8*)(Wl + off);
    }
    __syncthreads();
    bf16x8 ah[4], al[4];
    #pragma unroll
    for (int mt = 0; mt < 4; ++mt) {
      ah[mt] = *(const bf16x8*)&Ah[mh * 64 + mt * 16 + q][quad * 8];
      al[mt] = *(const bf16x8*)&Al[mh * 64 + mt * 16 + q][quad * 8];
    }
    #pragma unroll
    for (int tt = 0; tt < 6; ++tt) {
      bf16x8 bh = *(const bf16x8*)&WhS[ng * 128 + tt * 16 + q][quad * 8];
      bf16x8 bl = *(const bf16x8*)&WlS[ng * 128 + tt * 16 + q][quad * 8];
      #pragma unroll
      for (int mt = 0; mt < 4; ++mt) {
        acc[mt][tt] = MFMA16(ah[mt], bh, acc[mt][tt]);
        acc[mt][tt] = MFMA16(ah[mt], bl, acc[mt][tt]);
        acc[mt][tt] = MFMA16(al[mt], bh, acc[mt][tt]);
      }
    }
  }
  // ---- phase 2: k in [256,384) — hidden part; tiles {0,1,2,3,6,7}; 2-term ----
  for (int kc = 8; kc < 12; ++kc) {
    const int k0 = kc * 32;
    __syncthreads();
    #pragma unroll
    for (int p = 0; p < 2; ++p) {
      int i = p * 256 + t;
      int m = i >> 2, seg = i & 3;
      *(bf16x8*)&Ah[m][seg * 8] =
          *(const bf16x8*)(Z_hi + (rbase + m) * 384 + k0 + seg * 8);
    }
    #pragma unroll
    for (int p = 0; p < 4; ++p) {
      int i = p * 256 + t;
      int j = i >> 2, seg = i & 3;
      size_t off = (size_t)(nh * 256 + j) * 384 + k0 + seg * 8;
      *(bf16x8*)&WhS[j][seg * 8] = *(const bf16x8*)(Wh + off);
      *(bf16x8*)&WlS[j][seg * 8] = *(const bf16x8*)(Wl + off);
    }
    __syncthreads();
    bf16x8 ah[4];
    #pragma unroll
    for (int mt = 0; mt < 4; ++mt)
      ah[mt] = *(const bf16x8*)&Ah[mh * 64 + mt * 16 + q][quad * 8];
    #pragma unroll
    for (int ti = 0; ti < 6; ++ti) {
      const int tt = (ti < 4) ? ti : ti + 2;   // tiles 0,1,2,3,6,7
      bf16x8 bh = *(const bf16x8*)&WhS[ng * 128 + tt * 16 + q][quad * 8];
      bf16x8 bl = *(const bf16x8*)&WlS[ng * 128 + tt * 16 + q][quad * 8];
      #pragma unroll
      for (int mt = 0; mt < 4; ++mt) {
        acc[mt][tt] = MFMA16(ah[mt], bh, acc[mt][tt]);
        acc[mt][tt] = MFMA16(ah[mt], bl, acc[mt][tt]);
      }
    }
  }
  // gates epilogue
  #pragma unroll
  for (int s = 0; s < 2; ++s) {
    int c = nh * 64 + ng * 32 + s * 16 + q;
    int jb = nh * 256 + ng * 128;
    float bs_r  = bsum[jb + (0 * 2 + s) * 16 + q];
    float bs_i  = bsum[jb + (1 * 2 + s) * 16 + q];
    float bs_ni = bsum[jb + (2 * 2 + s) * 16 + q];
    float bs_nh = bsum[jb + (3 * 2 + s) * 16 + q];
    #pragma unroll
    for (int mt = 0; mt < 4; ++mt) {
      #pragma unroll
      for (int r = 0; r < 4; ++r) {
        size_t row = rbase + mh * 64 + mt * 16 + quad * 4 + r;
        float sr  = acc[mt][0 + s][r] + bs_r;
        float si  = acc[mt][2 + s][r] + bs_i;
        float ani = acc[mt][4 + s][r] + bs_ni;
        float anh = acc[mt][6 + s][r] + bs_nh;
        float g_rs = 1.f / (1.f + expf(-sr));
        float g_in = 1.f / (1.f + expf(-si));
        float g_ot = tanhf(ani + g_rs * anh);
        float h = bf2f(Z_hi[row * 384 + 256 + c]);
        out[row * 128 + c] = g_ot + g_in * (h - g_ot);
      }
    }
  }
}

extern "C" void kernel_launch(void* const* d_in, const int* in_sizes, int n_in,
                              void* d_out, int out_size, void* d_ws, size_t ws_size,
                              hipStream_t stream) {
  const int*   x     = (const int*)d_in[0];
  const float* A     = (const float*)d_in[1];
  const float* emb   = (const float*)d_in[2];
  const float* w_in  = (const float*)d_in[3];
  const float* b_in  = (const float*)d_in[4];
  const float* w_out = (const float*)d_in[5];
  const float* b_out = (const float*)d_in[6];
  const float* w_ih  = (const float*)d_in[7];
  const float* b_ih  = (const float*)d_in[8];
  const float* w_hh  = (const float*)d_in[9];
  const float* b_hh  = (const float*)d_in[10];
  const float* b_iah = (const float*)d_in[11];
  const float* b_oah = (const float*)d_in[12];
  float* out = (float*)d_out;
  char* ws = (char*)d_ws;

  if (ws_size < WS_BYTES) return;

  unsigned short* Z_hi = (unsigned short*)(ws + OFF_ZHI);
  unsigned short* Z_lo = (unsigned short*)(ws + OFF_ZLO);
  unsigned short* hvT  = (unsigned short*)(ws + OFF_HVT);
  unsigned short* hoT  = (unsigned short*)(ws + OFF_HOT);
  float* wInT  = (float*)(ws + OFF_WINT);
  float* wOutT = (float*)(ws + OFF_WOUTT);
  unsigned short* Wh = (unsigned short*)(ws + OFF_WH);
  unsigned short* Wl = (unsigned short*)(ws + OFF_WL);
  float* bsum = (float*)(ws + OFF_BSUM);

  ktranspose<<<(128 * 128 + 255) / 256, 256, 0, stream>>>(wInT, w_in, 128, 128);
  ktranspose<<<(128 * 128 + 255) / 256, 256, 0, stream>>>(wOutT, w_out, 128, 128);
  wcat_build<<<(512 * 384 + 255) / 256, 256, 0, stream>>>(w_ih, w_hh, b_ih, b_hh,
                                                          Wh, Wl, bsum);
  dim3 g1(BB, 7);
  k1_hvho<<<g1, 256, 0, stream>>>(x, emb, wInT, wOutT, b_in, b_out, hvT, hoT, Z_hi);
  dim3 g2(BB, 4);
  k2_amm<<<g2, 256, 0, stream>>>(A, hvT, hoT, b_iah, b_oah, Z_hi, Z_lo);
  dim3 g3(BNROWS / 128, 2);
  k3_gates<<<g3, 256, 0, stream>>>(Z_hi, Z_lo, Wh, Wl, bsum, out);
}